// Round 5
// baseline (806.193 us; speedup 1.0000x reference)
//
#include <hip/hip_runtime.h>
#include <hip/hip_bf16.h>

typedef unsigned short u16;
typedef __bf16 bf16x8 __attribute__((ext_vector_type(8)));   // MFMA A/B operand (4 VGPRs)
typedef float  f32x4  __attribute__((ext_vector_type(4)));   // MFMA C/D operand
typedef u16    u16x8  __attribute__((ext_vector_type(8)));

#define HID   96
#define LDP   104          // padded LDS row stride (bf16 elems); 208B rows, 16B-aligned
#define MROWS 93312        // B*N*D
#define BN    10368        // B*N
#define GRID_TILE 1458     // MROWS/64

// prepped-weight layout (u16 units): 12 chunks of 96x104, then Wih 384x104, Whh 384x104
#define PW_CHUNK 9984          // 96*104
#define PW_IH    119808        // 12*9984
#define PW_HH    159744        // PW_IH + 384*104
#define PW_TOTAL 199680

#define MFMA(a,b,c) __builtin_amdgcn_mfma_f32_16x16x32_bf16((a),(b),(c),0,0,0)

__device__ __forceinline__ float bf2f(u16 x){
  union { float f; unsigned u; } v; v.u = ((unsigned)x) << 16; return v.f;
}
__device__ __forceinline__ u16 f2bf(float f){
  union { float f; unsigned u; } v; v.f = f;
  unsigned r = v.u + 0x7fffu + ((v.u >> 16) & 1u);   // RNE
  return (u16)(r >> 16);
}
__device__ __forceinline__ float sigf(float x){ return 1.f/(1.f + __expf(-x)); }
__device__ __forceinline__ float tanhf_(float x){
  float xx = fminf(fmaxf(x, -15.f), 15.f);
  float e = __expf(-2.f * xx);
  return (1.f - e) / (1.f + e);
}

// ---- fragment loaders -------------------------------------------------------
struct Frags { bf16x8 a0, a1, a2; };

__device__ __forceinline__ Frags load_afrags_g(const u16* __restrict__ A, size_t row0, int lane){
  int t16 = lane & 15, q = lane >> 4;
  const u16* p = A + (row0 + (size_t)t16) * 96 + q * 8;
  Frags f;
  f.a0 = *reinterpret_cast<const bf16x8*>(p);
  f.a1 = *reinterpret_cast<const bf16x8*>(p + 32);
  f.a2 = *reinterpret_cast<const bf16x8*>(p + 64);
  return f;
}
__device__ __forceinline__ Frags load_afrags_s(const u16* sA, int row0, int lane){
  int t16 = lane & 15, q = lane >> 4;
  const u16* p = sA + (row0 + t16) * LDP + q * 8;
  Frags f;
  f.a0 = *reinterpret_cast<const bf16x8*>(p);
  f.a1 = *reinterpret_cast<const bf16x8*>(p + 32);
  f.a2 = *reinterpret_cast<const bf16x8*>(p + 64);
  return f;
}

// ---- staging: prepped bf16 weights, pure 16B memcpy into LDS ---------------
__device__ __forceinline__ void stage_pw(const u16* __restrict__ p, u16* sW, int tid){
  #pragma unroll
  for (int i = 0; i < 5; i++){                 // 1248 16B-chunks = 96*104/8
    int idx = tid + i * 256;
    if (idx < 1248)
      *reinterpret_cast<u16x8*>(sW + idx * 8) = *reinterpret_cast<const u16x8*>(p + idx * 8);
  }
}

// 6 col-tiles (one 96-row weight chunk) accumulated into acc[tbase..tbase+6)
__device__ __forceinline__ void mfma6(f32x4* acc, int tbase, Frags f,
    const u16* sW, int t16, int q)
{
  #pragma unroll
  for (int jt = 0; jt < 6; jt++){
    const u16* wr = sW + (jt * 16 + t16) * LDP + q * 8;
    acc[tbase + jt] = MFMA(f.a0, *reinterpret_cast<const bf16x8*>(wr),      acc[tbase + jt]);
    acc[tbase + jt] = MFMA(f.a1, *reinterpret_cast<const bf16x8*>(wr + 32), acc[tbase + jt]);
    acc[tbase + jt] = MFMA(f.a2, *reinterpret_cast<const bf16x8*>(wr + 64), acc[tbase + jt]);
  }
}

// one 16x96 layer for the calling wave
__device__ __forceinline__ void waves_layer(Frags f, const u16* sW,
    const float* __restrict__ bias, u16* dst, int dstStride, size_t rowBase,
    bool relu, int lane)
{
  int t16 = lane & 15, q = lane >> 4;
  #pragma unroll
  for (int nt = 0; nt < 6; nt++){
    float b = bias[nt * 16 + t16];
    f32x4 acc = {b, b, b, b};
    const u16* wr = sW + (nt * 16 + t16) * LDP + q * 8;
    acc = MFMA(f.a0, *reinterpret_cast<const bf16x8*>(wr),      acc);
    acc = MFMA(f.a1, *reinterpret_cast<const bf16x8*>(wr + 32), acc);
    acc = MFMA(f.a2, *reinterpret_cast<const bf16x8*>(wr + 64), acc);
    #pragma unroll
    for (int j = 0; j < 4; j++){
      float v = acc[j];
      if (relu) v = fmaxf(v, 0.f);
      dst[(rowBase + q * 4 + j) * (size_t)dstStride + nt * 16 + t16] = f2bf(v);
    }
  }
}

// ============================================================================
// K_prep: one-time f32->bf16 weight conversion into the exact LDS image.
__global__ __launch_bounds__(256) void k_prep(const float* __restrict__ crW,
    const float* __restrict__ drW, const float* __restrict__ gmW1,
    const float* __restrict__ gmW2, const float* __restrict__ rW12,
    const float* __restrict__ Wih, const float* __restrict__ Whh,
    u16* __restrict__ pW)
{
  int b = blockIdx.x, tid = threadIdx.x;
  if (b < 12){
    const float* src;
    if (b < 3)       src = crW  + b * 9216;
    else if (b < 6)  src = drW  + (b - 3) * 9216;
    else if (b == 6) src = gmW1 + 9216;
    else if (b == 7) src = gmW1 + 18432;
    else if (b < 10) src = gmW2 + (b - 8) * 9216;
    else             src = rW12 + (b - 10) * 9216;
    u16* dst = pW + b * PW_CHUNK;
    #pragma unroll
    for (int i = 0; i < 36; i++){
      int idx = tid + i * 256;
      int k = idx / 96, n = idx - k * 96;      // src row-major [k][n]
      dst[n * LDP + k] = f2bf(src[idx]);       // dst [n][k]
    }
  } else {
    int bb = b - 12;                           // 0,1: Wih halves; 2,3: Whh halves
    const float* src = (bb < 2 ? Wih : Whh) + (bb & 1) * 18432;
    u16* dst = pW + (bb < 2 ? PW_IH : PW_HH) + (bb & 1) * 19968;
    #pragma unroll
    for (int i = 0; i < 72; i++){
      int idx = tid + i * 256;
      int r = idx / 96, k = idx - r * 96;
      dst[r * LDP + k] = f2bf(src[idx]);
    }
  }
}

// K0: tables (f32)
__global__ void k_tables(const float* __restrict__ eW1, const float* __restrict__ eb1,
                         const float* __restrict__ eW2, const float* __restrict__ eb2,
                         const float* __restrict__ gmW1, const float* __restrict__ gmb1,
                         float* __restrict__ XTab, float* __restrict__ XgTab)
{
  __shared__ float sX[3][96];
  int j = threadIdx.x;
  if (j < 96){
    for (int ch = 0; ch < 3; ch++){
      float acc = eb2[j];
      for (int e = 0; e < 16; e++){
        float hv = fmaxf(eW1[ch * 16 + e] + eb1[e], 0.f);
        acc += hv * eW2[e * 96 + j];
      }
      sX[ch][j] = acc;
      XTab[ch * 96 + j] = acc;
    }
  }
  __syncthreads();
  if (j < 96){
    for (int ch = 0; ch < 3; ch++){
      float acc = gmb1[j];
      for (int k = 0; k < 96; k++) acc += sX[ch][k] * gmW1[k * 96 + j];
      XgTab[ch * 96 + j] = acc;
    }
  }
}

// K_init
__global__ __launch_bounds__(256) void k_init(const int* __restrict__ inputs,
    const float* __restrict__ c0, const float* __restrict__ XTab,
    u16* __restrict__ h, float* __restrict__ c)
{
  int idx = blockIdx.x * 256 + threadIdx.x;     // exactly MROWS*12
  int m = idx / 12, h8 = idx - m * 12;
  int bn = m / 9, d = m - bn * 9;
  int inp = inputs[bn];
  int ch = (inp == 0) ? 0 : ((inp == d + 1) ? 1 : 2);
  const float* xt = XTab + ch * 96 + h8 * 8;
  u16* hp = h + (size_t)m * 96 + h8 * 8;
  #pragma unroll
  for (int e = 0; e < 8; e++) hp[e] = f2bf(xt[e]);
  const float* cs = c0 + (size_t)m * 96 + h8 * 8;
  float* cp = c + (size_t)m * 96 + h8 * 8;
  #pragma unroll
  for (int e = 0; e < 8; e++) cp[e] = cs[e];
}

// K_AB: fused dual 3-layer MLP (cr -> B1, dr -> B2), ping-pong staged weights
__global__ __launch_bounds__(256) void k_ab(const u16* __restrict__ h,
    u16* __restrict__ B1, u16* __restrict__ B2,
    const u16* __restrict__ pW, const float* __restrict__ crB,
    const float* __restrict__ drB)
{
  __shared__ u16 sW0[96 * LDP];
  __shared__ u16 sW1[96 * LDP];
  __shared__ u16 sA[64 * LDP];                 // wave-private 16-row slices
  const int tid = threadIdx.x, lane = tid & 63, wave = tid >> 6;
  const int wrow = wave * 16;
  const size_t rbase = (size_t)blockIdx.x * 64;

  stage_pw(pW, sW0, tid);                      // cr L0
  Frags hf = load_afrags_g(h, rbase + wrow, lane);
  __syncthreads();

  waves_layer(hf, sW0, crB, sA, LDP, wrow, true, lane);
  stage_pw(pW + PW_CHUNK, sW1, tid);           // cr L1
  __syncthreads();

  { Frags f = load_afrags_s(sA, wrow, lane);
    waves_layer(f, sW1, crB + 96, sA, LDP, wrow, true, lane); }
  stage_pw(pW + 2 * PW_CHUNK, sW0, tid);       // cr L2
  __syncthreads();

  { Frags f = load_afrags_s(sA, wrow, lane);
    waves_layer(f, sW0, crB + 192, B1, 96, rbase + wrow, false, lane); }
  stage_pw(pW + 3 * PW_CHUNK, sW1, tid);       // dr L0
  __syncthreads();

  waves_layer(hf, sW1, drB, sA, LDP, wrow, true, lane);
  stage_pw(pW + 4 * PW_CHUNK, sW0, tid);       // dr L1
  __syncthreads();

  { Frags f = load_afrags_s(sA, wrow, lane);
    waves_layer(f, sW0, drB + 96, sA, LDP, wrow, true, lane); }
  stage_pw(pW + 5 * PW_CHUNK, sW1, tid);       // dr L2
  __syncthreads();

  { Frags f = load_afrags_s(sA, wrow, lane);
    waves_layer(f, sW1, drB + 192, B2, 96, rbase + wrow, false, lane); }
}

// K3: msg_cell in-place
__global__ __launch_bounds__(256) void k_msgcell(u16* __restrict__ buf)
{
  int idx = blockIdx.x * 256 + threadIdx.x;     // exactly BN*12
  int bn = idx / 12, h8 = idx - bn * 12;
  u16* base = buf + (size_t)bn * 864 + h8 * 8;
  u16x8 v[9];
  #pragma unroll
  for (int d = 0; d < 9; d++) v[d] = *reinterpret_cast<const u16x8*>(base + d * 96);
  float s[8];
  #pragma unroll
  for (int e = 0; e < 8; e++) s[e] = 0.f;
  #pragma unroll
  for (int d = 0; d < 9; d++)
    #pragma unroll
    for (int e = 0; e < 8; e++) s[e] += bf2f(v[d][e]);
  #pragma unroll
  for (int d = 0; d < 9; d++){
    u16x8 o;
    #pragma unroll
    for (int e = 0; e < 8; e++) o[e] = f2bf(s[e] - bf2f(v[d][e]));
    *reinterpret_cast<u16x8*>(base + d * 96) = o;
  }
}

__device__ __forceinline__ void addrow(float* s, const u16* p){
  u16x8 t = *reinterpret_cast<const u16x8*>(p);
  #pragma unroll
  for (int e = 0; e < 8; e++) s[e] += bf2f(t[e]);
}

// K4: msg_digit in-place per (b,d) slice
__global__ __launch_bounds__(256) void k_msgdigit(u16* __restrict__ buf)
{
  __shared__ u16 sT[81 * LDP];
  const int tid = threadIdx.x;
  const int b = blockIdx.x / 9, d = blockIdx.x - b * 9;
  const size_t base = ((size_t)b * 729 + d) * 96;
  for (int i = tid; i < 972; i += 256){
    int n = i / 12, k8 = i - n * 12;
    *reinterpret_cast<u16x8*>(sT + n * LDP + k8 * 8) =
      *reinterpret_cast<const u16x8*>(buf + base + (size_t)n * 864 + k8 * 8);
  }
  __syncthreads();
  for (int i = tid; i < 972; i += 256){
    int m = i / 12, k8 = i - m * 12;
    int r = m / 9, cc = m - r * 9;
    int br = (r / 3) * 3, bc = (cc / 3) * 3;
    float s[8];
    #pragma unroll
    for (int e = 0; e < 8; e++) s[e] = 0.f;
    #pragma unroll
    for (int c2 = 0; c2 < 9; c2++) if (c2 != cc) addrow(s, sT + (r * 9 + c2) * LDP + k8 * 8);
    #pragma unroll
    for (int r2 = 0; r2 < 9; r2++) if (r2 != r) addrow(s, sT + (r2 * 9 + cc) * LDP + k8 * 8);
    #pragma unroll
    for (int r2 = 0; r2 < 3; r2++)
      #pragma unroll
      for (int c2 = 0; c2 < 3; c2++){
        int rr = br + r2, c3 = bc + c2;
        if (rr != r && c3 != cc) addrow(s, sT + (rr * 9 + c3) * LDP + k8 * 8);
      }
    u16x8 o;
    #pragma unroll
    for (int e = 0; e < 8; e++) o[e] = f2bf(s[e]);
    *reinterpret_cast<u16x8*>(buf + base + (size_t)m * 864 + k8 * 8) = o;
  }
}

// K_GLR: graph-merge + LSTM + readout, fused; ping-pong staged weights.
__global__ __launch_bounds__(256) void k_glr(const u16* __restrict__ mcell,
    const u16* __restrict__ mdig, const int* __restrict__ inputs,
    const float* __restrict__ XgTab, const u16* __restrict__ pW,
    const float* __restrict__ gmb2, u16* __restrict__ h, float* __restrict__ c,
    const float* __restrict__ bih, const float* __restrict__ bhh,
    const float* __restrict__ rb12, const float* __restrict__ rW3,
    const float* __restrict__ rb3, float* __restrict__ out)
{
  __shared__ u16 sW0[96 * LDP];
  __shared__ u16 sW1[96 * LDP];
  __shared__ u16 sA[64 * LDP];                 // wave-private 16-row slices
  __shared__ float sw3[96];
  const int tid = threadIdx.x, lane = tid & 63, wave = tid >> 6;
  const int t16 = lane & 15, q = lane >> 4;
  const int wrow = wave * 16;
  const size_t rbase = (size_t)blockIdx.x * 64;

  if (tid < 96) sw3[tid] = rW3[tid];
  stage_pw(pW + 6 * PW_CHUNK, sW0, tid);       // gm W1b
  int ch[4];
  #pragma unroll
  for (int j = 0; j < 4; j++){
    int m = (int)rbase + wrow + q * 4 + j;
    int bn = m / 9, d = m - bn * 9;
    int inp = inputs[bn];
    ch[j] = (inp == 0) ? 0 : ((inp == d + 1) ? 1 : 2);
  }
  f32x4 acc6[6];
  #pragma unroll
  for (int nt = 0; nt < 6; nt++)
    #pragma unroll
    for (int j = 0; j < 4; j++)
      acc6[nt][j] = XgTab[ch[j] * 96 + nt * 16 + t16];
  __syncthreads();

  // P1: + mcell @ W1b
  { Frags f = load_afrags_g(mcell, rbase + wrow, lane);
    mfma6(acc6, 0, f, sW0, t16, q); }
  stage_pw(pW + 7 * PW_CHUNK, sW1, tid);       // gm W1c
  __syncthreads();

  // P2: + mdig @ W1c; relu -> sA (g1)
  { Frags f = load_afrags_g(mdig, rbase + wrow, lane);
    mfma6(acc6, 0, f, sW1, t16, q);
    #pragma unroll
    for (int nt = 0; nt < 6; nt++)
      #pragma unroll
      for (int j = 0; j < 4; j++)
        sA[(wrow + q * 4 + j) * LDP + nt * 16 + t16] = f2bf(fmaxf(acc6[nt][j], 0.f));
  }
  stage_pw(pW + 8 * PW_CHUNK, sW0, tid);       // gm W2_0
  __syncthreads();

  // P3: g2 = relu(g1 @ W2_0 + b) -> sA
  { Frags f = load_afrags_s(sA, wrow, lane);
    waves_layer(f, sW0, gmb2, sA, LDP, wrow, true, lane); }
  stage_pw(pW + 9 * PW_CHUNK, sW1, tid);       // gm W2_1
  __syncthreads();

  // P4: g = g2 @ W2_1 + b (no relu) -> sA (LSTM x-input)
  { Frags f = load_afrags_s(sA, wrow, lane);
    waves_layer(f, sW1, gmb2 + 96, sA, LDP, wrow, false, lane); }
  stage_pw(pW + PW_IH, sW0, tid);              // Wih chunk 0
  __syncthreads();

  // LSTM: 24 gate tiles, ping-pong over 8 x 96-row weight chunks
  f32x4 acc[24];
  #pragma unroll
  for (int t = 0; t < 24; t++){
    int n = t * 16 + t16;
    float b = bih[n] + bhh[n];
    f32x4 a = {b, b, b, b};
    acc[t] = a;
  }
  Frags ax = load_afrags_s(sA, wrow, lane);
  Frags ah = load_afrags_g(h, rbase + wrow, lane);

  mfma6(acc, 0, ax, sW0, t16, q);  stage_pw(pW + PW_IH + 1 * PW_CHUNK, sW1, tid); __syncthreads();
  mfma6(acc, 6, ax, sW1, t16, q);  stage_pw(pW + PW_IH + 2 * PW_CHUNK, sW0, tid); __syncthreads();
  mfma6(acc, 12, ax, sW0, t16, q); stage_pw(pW + PW_IH + 3 * PW_CHUNK, sW1, tid); __syncthreads();
  mfma6(acc, 18, ax, sW1, t16, q); stage_pw(pW + PW_HH + 0 * PW_CHUNK, sW0, tid); __syncthreads();
  mfma6(acc, 0, ah, sW0, t16, q);  stage_pw(pW + PW_HH + 1 * PW_CHUNK, sW1, tid); __syncthreads();
  mfma6(acc, 6, ah, sW1, t16, q);  stage_pw(pW + PW_HH + 2 * PW_CHUNK, sW0, tid); __syncthreads();
  mfma6(acc, 12, ah, sW0, t16, q); stage_pw(pW + PW_HH + 3 * PW_CHUNK, sW1, tid); __syncthreads();
  mfma6(acc, 18, ah, sW1, t16, q); stage_pw(pW + 10 * PW_CHUNK, sW0, tid);        __syncthreads();

  // Epilogue: c/h update; h_new -> global + sA (for readout)
  #pragma unroll
  for (int jt = 0; jt < 6; jt++)
    #pragma unroll
    for (int j = 0; j < 4; j++){
      size_t m = rbase + wrow + q * 4 + j;
      int col = jt * 16 + t16;
      float iv = acc[0 * 6 + jt][j];
      float fv = acc[1 * 6 + jt][j];
      float gv = acc[2 * 6 + jt][j];
      float ov = acc[3 * 6 + jt][j];
      float cold = c[m * 96 + col];
      float cn = sigf(fv) * cold + sigf(iv) * tanhf_(gv);
      float hn = sigf(ov) * tanhf_(cn);
      c[m * 96 + col] = cn;
      u16 hb = f2bf(hn);
      h[m * 96 + col] = hb;
      sA[(wrow + q * 4 + j) * LDP + col] = hb;
    }

  // Readout layer 1 (rW12_0 already in sW0)
  { Frags f = load_afrags_s(sA, wrow, lane);
    waves_layer(f, sW0, rb12, sA, LDP, wrow, true, lane); }
  stage_pw(pW + 11 * PW_CHUNK, sW1, tid);
  __syncthreads();

  // Readout layer 2
  { Frags f = load_afrags_s(sA, wrow, lane);
    waves_layer(f, sW1, rb12 + 96, sA, LDP, wrow, true, lane); }
  __syncthreads();                             // cross-wave reads in final dot

  // Final dot: out[row] = sA[row,:] . w3 + b3
  int row = tid >> 2, part = tid & 3;
  float s = 0.f;
  const u16* rp = sA + row * LDP + part * 24;
  #pragma unroll
  for (int k = 0; k < 24; k++) s += bf2f(rp[k]) * sw3[part * 24 + k];
  s += __shfl_xor(s, 1);
  s += __shfl_xor(s, 2);
  if (part == 0) out[rbase + row] = s + rb3[0];
}

// ============================================================================
extern "C" void kernel_launch(void* const* d_in, const int* in_sizes, int n_in,
                              void* d_out, int out_size, void* d_ws, size_t ws_size,
                              hipStream_t stream)
{
  (void)in_sizes; (void)n_in; (void)out_size; (void)ws_size;
  const int*   inputs = (const int*)d_in[0];
  const float* c0     = (const float*)d_in[1];
  const float* eW1  = (const float*)d_in[4];
  const float* eb1  = (const float*)d_in[5];
  const float* eW2  = (const float*)d_in[6];
  const float* eb2  = (const float*)d_in[7];
  const float* crW  = (const float*)d_in[8];
  const float* crB  = (const float*)d_in[9];
  const float* drW  = (const float*)d_in[10];
  const float* drB  = (const float*)d_in[11];
  const float* gmW1 = (const float*)d_in[12];
  const float* gmb1 = (const float*)d_in[13];
  const float* gmW2 = (const float*)d_in[14];
  const float* gmb2 = (const float*)d_in[15];
  const float* Wih  = (const float*)d_in[16];
  const float* Whh  = (const float*)d_in[17];
  const float* bih  = (const float*)d_in[18];
  const float* bhh  = (const float*)d_in[19];
  const float* rW12 = (const float*)d_in[20];
  const float* rb12 = (const float*)d_in[21];
  const float* rW3  = (const float*)d_in[22];
  const float* rb3  = (const float*)d_in[23];

  char* ws = (char*)d_ws;
  float* XgTab = (float*)(ws);
  float* XTab  = (float*)(ws + 4096);
  u16*   pW    = (u16*)(ws + 8192);
  u16* h  = (u16*)(ws + 8192 + 401408);
  u16* B1 = h  + (size_t)MROWS * 96;
  u16* B2 = B1 + (size_t)MROWS * 96;
  float* c = (float*)(B2 + (size_t)MROWS * 96);
  float* out = (float*)d_out;

  k_prep<<<16, 256, 0, stream>>>(crW, drW, gmW1, gmW2, rW12, Wih, Whh, pW);
  k_tables<<<1, 128, 0, stream>>>(eW1, eb1, eW2, eb2, gmW1, gmb1, XTab, XgTab);
  k_init<<<(MROWS * 12) / 256, 256, 0, stream>>>(inputs, c0, XTab, h, c);

  for (int it = 0; it < 4; ++it){
    k_ab<<<GRID_TILE, 256, 0, stream>>>(h, B1, B2, pW, crB, drB);
    k_msgcell<<<(BN * 12) / 256, 256, 0, stream>>>(B1);
    k_msgdigit<<<128 * 9, 256, 0, stream>>>(B2);
    k_glr<<<GRID_TILE, 256, 0, stream>>>(B1, B2, inputs, XgTab, pW, gmb2,
                                         h, c, bih, bhh, rb12, rW3, rb3,
                                         out + (size_t)it * MROWS);
  }
}

// Round 6
// 797.455 us; speedup vs baseline: 1.0110x; 1.0110x over previous
//
#include <hip/hip_runtime.h>
#include <hip/hip_bf16.h>

typedef unsigned short u16;
typedef __bf16 bf16x8 __attribute__((ext_vector_type(8)));   // MFMA A/B operand (4 VGPRs)
typedef float  f32x4  __attribute__((ext_vector_type(4)));   // MFMA C/D operand
typedef u16    u16x8  __attribute__((ext_vector_type(8)));

#define HID   96
#define LDP   104          // padded LDS row stride (bf16 elems); 208B rows, 16B-aligned
#define MROWS 93312        // B*N*D
#define BN    10368        // B*N
#define GRID_TILE 1458     // MROWS/64

// prepped-weight layout (u16 units): 12 chunks of 96x104, then Wih 384x104, Whh 384x104
#define PW_CHUNK 9984          // 96*104
#define PW_IH    119808        // 12*9984
#define PW_HH    159744        // PW_IH + 384*104
#define PW_TOTAL 199680

#define MFMA(a,b,c) __builtin_amdgcn_mfma_f32_16x16x32_bf16((a),(b),(c),0,0,0)

__device__ __forceinline__ float bf2f(u16 x){
  union { float f; unsigned u; } v; v.u = ((unsigned)x) << 16; return v.f;
}
__device__ __forceinline__ u16 f2bf(float f){
  union { float f; unsigned u; } v; v.f = f;
  unsigned r = v.u + 0x7fffu + ((v.u >> 16) & 1u);   // RNE
  return (u16)(r >> 16);
}
__device__ __forceinline__ float sigf(float x){ return 1.f/(1.f + __expf(-x)); }
__device__ __forceinline__ float tanhf_(float x){
  float xx = fminf(fmaxf(x, -15.f), 15.f);
  float e = __expf(-2.f * xx);
  return (1.f - e) / (1.f + e);
}

// ---- fragment loaders -------------------------------------------------------
struct Frags { bf16x8 a0, a1, a2; };

__device__ __forceinline__ Frags load_afrags_g(const u16* __restrict__ A, size_t row0, int lane){
  int t16 = lane & 15, q = lane >> 4;
  const u16* p = A + (row0 + (size_t)t16) * 96 + q * 8;
  Frags f;
  f.a0 = *reinterpret_cast<const bf16x8*>(p);
  f.a1 = *reinterpret_cast<const bf16x8*>(p + 32);
  f.a2 = *reinterpret_cast<const bf16x8*>(p + 64);
  return f;
}
__device__ __forceinline__ Frags load_afrags_s(const u16* sA, int row0, int lane){
  int t16 = lane & 15, q = lane >> 4;
  const u16* p = sA + (row0 + t16) * LDP + q * 8;
  Frags f;
  f.a0 = *reinterpret_cast<const bf16x8*>(p);
  f.a1 = *reinterpret_cast<const bf16x8*>(p + 32);
  f.a2 = *reinterpret_cast<const bf16x8*>(p + 64);
  return f;
}

// ---- staging: depth-2 pipeline (regs hold next chunk during current phase) --
struct Pre { u16x8 v[5]; };
__device__ __forceinline__ Pre load_pre(const u16* __restrict__ p, int tid){
  Pre r;
  #pragma unroll
  for (int i = 0; i < 4; i++)
    r.v[i] = *reinterpret_cast<const u16x8*>(p + (tid + i * 256) * 8);
  if (tid < 224) r.v[4] = *reinterpret_cast<const u16x8*>(p + (tid + 1024) * 8);
  return r;
}
__device__ __forceinline__ void write_pre(const Pre& r, u16* sW, int tid){
  #pragma unroll
  for (int i = 0; i < 4; i++)
    *reinterpret_cast<u16x8*>(sW + (tid + i * 256) * 8) = r.v[i];
  if (tid < 224) *reinterpret_cast<u16x8*>(sW + (tid + 1024) * 8) = r.v[4];
}
__device__ __forceinline__ void stage_direct(const u16* __restrict__ p, u16* sW, int tid){
  Pre r = load_pre(p, tid);
  write_pre(r, sW, tid);
}

// 6 col-tiles accumulated into acc[tbase..tbase+6)
__device__ __forceinline__ void mfma6(f32x4* acc, int tbase, Frags f,
    const u16* sW, int t16, int q)
{
  #pragma unroll
  for (int jt = 0; jt < 6; jt++){
    const u16* wr = sW + (jt * 16 + t16) * LDP + q * 8;
    acc[tbase + jt] = MFMA(f.a0, *reinterpret_cast<const bf16x8*>(wr),      acc[tbase + jt]);
    acc[tbase + jt] = MFMA(f.a1, *reinterpret_cast<const bf16x8*>(wr + 32), acc[tbase + jt]);
    acc[tbase + jt] = MFMA(f.a2, *reinterpret_cast<const bf16x8*>(wr + 64), acc[tbase + jt]);
  }
}

// one 16x96 layer for the calling wave
__device__ __forceinline__ void waves_layer(Frags f, const u16* sW,
    const float* __restrict__ bias, u16* dst, int dstStride, size_t rowBase,
    bool relu, int lane)
{
  int t16 = lane & 15, q = lane >> 4;
  #pragma unroll
  for (int nt = 0; nt < 6; nt++){
    float b = bias[nt * 16 + t16];
    f32x4 acc = {b, b, b, b};
    const u16* wr = sW + (nt * 16 + t16) * LDP + q * 8;
    acc = MFMA(f.a0, *reinterpret_cast<const bf16x8*>(wr),      acc);
    acc = MFMA(f.a1, *reinterpret_cast<const bf16x8*>(wr + 32), acc);
    acc = MFMA(f.a2, *reinterpret_cast<const bf16x8*>(wr + 64), acc);
    #pragma unroll
    for (int j = 0; j < 4; j++){
      float v = acc[j];
      if (relu) v = fmaxf(v, 0.f);
      dst[(rowBase + q * 4 + j) * (size_t)dstStride + nt * 16 + t16] = f2bf(v);
    }
  }
}

// ============================================================================
// K_prep: one-time f32->bf16 weight conversion into the exact LDS image.
__global__ __launch_bounds__(256) void k_prep(const float* __restrict__ crW,
    const float* __restrict__ drW, const float* __restrict__ gmW1,
    const float* __restrict__ gmW2, const float* __restrict__ rW12,
    const float* __restrict__ Wih, const float* __restrict__ Whh,
    u16* __restrict__ pW)
{
  int b = blockIdx.x, tid = threadIdx.x;
  if (b < 12){
    const float* src;
    if (b < 3)       src = crW  + b * 9216;
    else if (b < 6)  src = drW  + (b - 3) * 9216;
    else if (b == 6) src = gmW1 + 9216;
    else if (b == 7) src = gmW1 + 18432;
    else if (b < 10) src = gmW2 + (b - 8) * 9216;
    else             src = rW12 + (b - 10) * 9216;
    u16* dst = pW + b * PW_CHUNK;
    #pragma unroll
    for (int i = 0; i < 36; i++){
      int idx = tid + i * 256;
      int k = idx / 96, n = idx - k * 96;      // src row-major [k][n]
      dst[n * LDP + k] = f2bf(src[idx]);       // dst [n][k]
    }
  } else {
    int bb = b - 12;                           // 0,1: Wih halves; 2,3: Whh halves
    const float* src = (bb < 2 ? Wih : Whh) + (bb & 1) * 18432;
    u16* dst = pW + (bb < 2 ? PW_IH : PW_HH) + (bb & 1) * 19968;
    #pragma unroll
    for (int i = 0; i < 72; i++){
      int idx = tid + i * 256;
      int r = idx / 96, k = idx - r * 96;
      dst[r * LDP + k] = f2bf(src[idx]);
    }
  }
}

// K0: tables (f32) + zero-bias vector
__global__ void k_tables(const float* __restrict__ eW1, const float* __restrict__ eb1,
                         const float* __restrict__ eW2, const float* __restrict__ eb2,
                         const float* __restrict__ gmW1, const float* __restrict__ gmb1,
                         float* __restrict__ XTab, float* __restrict__ XgTab,
                         float* __restrict__ zb)
{
  __shared__ float sX[3][96];
  int j = threadIdx.x;
  if (j < 96){
    zb[j] = 0.f;
    for (int ch = 0; ch < 3; ch++){
      float acc = eb2[j];
      for (int e = 0; e < 16; e++){
        float hv = fmaxf(eW1[ch * 16 + e] + eb1[e], 0.f);
        acc += hv * eW2[e * 96 + j];
      }
      sX[ch][j] = acc;
      XTab[ch * 96 + j] = acc;
    }
  }
  __syncthreads();
  if (j < 96){
    for (int ch = 0; ch < 3; ch++){
      float acc = gmb1[j];
      for (int k = 0; k < 96; k++) acc += sX[ch][k] * gmW1[k * 96 + j];
      XgTab[ch * 96 + j] = acc;
    }
  }
}

// K_init: h only (c read directly from c0 on iter 0)
__global__ __launch_bounds__(256) void k_init(const int* __restrict__ inputs,
    const float* __restrict__ XTab, u16* __restrict__ h)
{
  int idx = blockIdx.x * 256 + threadIdx.x;     // exactly MROWS*12
  int m = idx / 12, h8 = idx - m * 12;
  int bn = m / 9, d = m - bn * 9;
  int inp = inputs[bn];
  int ch = (inp == 0) ? 0 : ((inp == d + 1) ? 1 : 2);
  const float* xt = XTab + ch * 96 + h8 * 8;
  u16* hp = h + (size_t)m * 96 + h8 * 8;
  #pragma unroll
  for (int e = 0; e < 8; e++) hp[e] = f2bf(xt[e]);
}

// K_AB2: h -> cr3 -> @W1b = Y (B1);  h -> dr3 -> @W1c = Z (B2). 8 layers, pipelined.
__global__ __launch_bounds__(256) void k_ab2(const u16* __restrict__ h,
    u16* __restrict__ Y, u16* __restrict__ Z,
    const u16* __restrict__ pW, const float* __restrict__ crB,
    const float* __restrict__ drB, const float* __restrict__ zb)
{
  __shared__ u16 sW0[96 * LDP];
  __shared__ u16 sW1[96 * LDP];
  __shared__ u16 sA[64 * LDP];
  const int tid = threadIdx.x, lane = tid & 63, wave = tid >> 6;
  const int wrow = wave * 16;
  const size_t rbase = (size_t)blockIdx.x * 64;

  stage_direct(pW, sW0, tid);                        // cr L0
  Pre pre = load_pre(pW + PW_CHUNK, tid);            // cr L1
  Frags hf = load_afrags_g(h, rbase + wrow, lane);
  __syncthreads();

  waves_layer(hf, sW0, crB, sA, LDP, wrow, true, lane);
  write_pre(pre, sW1, tid); pre = load_pre(pW + 2 * PW_CHUNK, tid);   // cr L2
  __syncthreads();

  { Frags f = load_afrags_s(sA, wrow, lane);
    waves_layer(f, sW1, crB + 96, sA, LDP, wrow, true, lane); }
  write_pre(pre, sW0, tid); pre = load_pre(pW + 6 * PW_CHUNK, tid);   // W1b
  __syncthreads();

  { Frags f = load_afrags_s(sA, wrow, lane);
    waves_layer(f, sW0, crB + 192, sA, LDP, wrow, false, lane); }     // cr L2 (no relu)
  write_pre(pre, sW1, tid); pre = load_pre(pW + 3 * PW_CHUNK, tid);   // dr L0
  __syncthreads();

  { Frags f = load_afrags_s(sA, wrow, lane);
    waves_layer(f, sW1, zb, Y, 96, rbase + wrow, false, lane); }      // Y = cr3 @ W1b
  write_pre(pre, sW0, tid); pre = load_pre(pW + 4 * PW_CHUNK, tid);   // dr L1
  __syncthreads();

  waves_layer(hf, sW0, drB, sA, LDP, wrow, true, lane);
  write_pre(pre, sW1, tid); pre = load_pre(pW + 5 * PW_CHUNK, tid);   // dr L2
  __syncthreads();

  { Frags f = load_afrags_s(sA, wrow, lane);
    waves_layer(f, sW1, drB + 96, sA, LDP, wrow, true, lane); }
  write_pre(pre, sW0, tid); pre = load_pre(pW + 7 * PW_CHUNK, tid);   // W1c
  __syncthreads();

  { Frags f = load_afrags_s(sA, wrow, lane);
    waves_layer(f, sW0, drB + 192, sA, LDP, wrow, false, lane); }     // dr L2 (no relu)
  write_pre(pre, sW1, tid);
  __syncthreads();

  { Frags f = load_afrags_s(sA, wrow, lane);
    waves_layer(f, sW1, zb, Z, 96, rbase + wrow, false, lane); }      // Z = dr3 @ W1c
}

// K_scell: Ssum[bn,:] = sum_d Y[bn,d,:]   (bf16 out)
__global__ __launch_bounds__(256) void k_scell(const u16* __restrict__ Y,
    u16* __restrict__ Ssum)
{
  int idx = blockIdx.x * 256 + threadIdx.x;     // exactly BN*12
  int bn = idx / 12, h8 = idx - bn * 12;
  const u16* base = Y + (size_t)bn * 864 + h8 * 8;
  float s[8];
  #pragma unroll
  for (int e = 0; e < 8; e++) s[e] = 0.f;
  #pragma unroll
  for (int d = 0; d < 9; d++){
    u16x8 v = *reinterpret_cast<const u16x8*>(base + d * 96);
    #pragma unroll
    for (int e = 0; e < 8; e++) s[e] += bf2f(v[e]);
  }
  u16x8 o;
  #pragma unroll
  for (int e = 0; e < 8; e++) o[e] = f2bf(s[e]);
  *reinterpret_cast<u16x8*>(Ssum + (size_t)bn * 96 + h8 * 8) = o;
}

__device__ __forceinline__ void addrow(float* s, const u16* p){
  u16x8 t = *reinterpret_cast<const u16x8*>(p);
  #pragma unroll
  for (int e = 0; e < 8; e++) s[e] += bf2f(t[e]);
}

// K4: msg_digit in-place per (b,d) slice (operates on Z)
__global__ __launch_bounds__(256) void k_msgdigit(u16* __restrict__ buf)
{
  __shared__ u16 sT[81 * LDP];
  const int tid = threadIdx.x;
  const int b = blockIdx.x / 9, d = blockIdx.x - b * 9;
  const size_t base = ((size_t)b * 729 + d) * 96;
  for (int i = tid; i < 972; i += 256){
    int n = i / 12, k8 = i - n * 12;
    *reinterpret_cast<u16x8*>(sT + n * LDP + k8 * 8) =
      *reinterpret_cast<const u16x8*>(buf + base + (size_t)n * 864 + k8 * 8);
  }
  __syncthreads();
  for (int i = tid; i < 972; i += 256){
    int m = i / 12, k8 = i - m * 12;
    int r = m / 9, cc = m - r * 9;
    int br = (r / 3) * 3, bc = (cc / 3) * 3;
    float s[8];
    #pragma unroll
    for (int e = 0; e < 8; e++) s[e] = 0.f;
    #pragma unroll
    for (int c2 = 0; c2 < 9; c2++) if (c2 != cc) addrow(s, sT + (r * 9 + c2) * LDP + k8 * 8);
    #pragma unroll
    for (int r2 = 0; r2 < 9; r2++) if (r2 != r) addrow(s, sT + (r2 * 9 + cc) * LDP + k8 * 8);
    #pragma unroll
    for (int r2 = 0; r2 < 3; r2++)
      #pragma unroll
      for (int c2 = 0; c2 < 3; c2++){
        int rr = br + r2, c3 = bc + c2;
        if (rr != r && c3 != cc) addrow(s, sT + (rr * 9 + c3) * LDP + k8 * 8);
      }
    u16x8 o;
    #pragma unroll
    for (int e = 0; e < 8; e++) o[e] = f2bf(s[e]);
    *reinterpret_cast<u16x8*>(buf + base + (size_t)m * 864 + k8 * 8) = o;
  }
}

// K_GLR2: elementwise g1 + gm W2 + LSTM + readout. 12 staged chunks, depth-2 pipeline.
__global__ __launch_bounds__(256) void k_glr2(const u16* __restrict__ Y,
    const u16* __restrict__ Zd, const u16* __restrict__ Ssum,
    const int* __restrict__ inputs, const float* __restrict__ XgTab,
    const u16* __restrict__ pW, const float* __restrict__ gmb2,
    u16* __restrict__ h, const float* __restrict__ cin, float* __restrict__ cout,
    const float* __restrict__ bih, const float* __restrict__ bhh,
    const float* __restrict__ rb12, const float* __restrict__ rW3,
    const float* __restrict__ rb3, float* __restrict__ out)
{
  __shared__ u16 sW0[96 * LDP];
  __shared__ u16 sW1[96 * LDP];
  __shared__ u16 sA[64 * LDP];
  __shared__ float sw3[96];
  const int tid = threadIdx.x, lane = tid & 63, wave = tid >> 6;
  const int t16 = lane & 15, q = lane >> 4;
  const int wrow = wave * 16;
  const size_t rbase = (size_t)blockIdx.x * 64;

  if (tid < 96) sw3[tid] = rW3[tid];
  // LSTM accumulators with biases (lives in AGPRs across phases)
  f32x4 acc[24];
  #pragma unroll
  for (int t = 0; t < 24; t++){
    int n = t * 16 + t16;
    float b = bih[n] + bhh[n];
    f32x4 a = {b, b, b, b};
    acc[t] = a;
  }
  Frags ah = load_afrags_g(h, rbase + wrow, lane);

  // P0: stage W2_0 direct; preload W2_1; elementwise g1 -> sA
  stage_direct(pW + 8 * PW_CHUNK, sW0, tid);
  Pre pre = load_pre(pW + 9 * PW_CHUNK, tid);
  for (int i = tid; i < 768; i += 256){
    int r = i / 12, kc = i - r * 12;
    int m = (int)rbase + r;
    int bn = m / 9, d = m - bn * 9;
    int inp = inputs[bn];
    int ch = (inp == 0) ? 0 : ((inp == d + 1) ? 1 : 2);
    const float* xg = XgTab + ch * 96 + kc * 8;
    u16x8 vy = *reinterpret_cast<const u16x8*>(Y    + (size_t)m * 96 + kc * 8);
    u16x8 vz = *reinterpret_cast<const u16x8*>(Zd   + (size_t)m * 96 + kc * 8);
    u16x8 vs = *reinterpret_cast<const u16x8*>(Ssum + (size_t)bn * 96 + kc * 8);
    u16x8 o;
    #pragma unroll
    for (int e = 0; e < 8; e++)
      o[e] = f2bf(fmaxf(xg[e] + bf2f(vs[e]) - bf2f(vy[e]) + bf2f(vz[e]), 0.f));
    *reinterpret_cast<u16x8*>(sA + r * LDP + kc * 8) = o;
  }
  __syncthreads();

  // P1: g2 = relu(g1@W2_0+b)
  { Frags f = load_afrags_s(sA, wrow, lane);
    waves_layer(f, sW0, gmb2, sA, LDP, wrow, true, lane); }
  write_pre(pre, sW1, tid); pre = load_pre(pW + PW_IH, tid);
  __syncthreads();

  // P2: x = g2@W2_1+b (no relu)
  { Frags f = load_afrags_s(sA, wrow, lane);
    waves_layer(f, sW1, gmb2 + 96, sA, LDP, wrow, false, lane); }
  write_pre(pre, sW0, tid); pre = load_pre(pW + PW_IH + PW_CHUNK, tid);
  __syncthreads();

  Frags ax = load_afrags_s(sA, wrow, lane);
  // P3..P10: LSTM 8 chunks
  mfma6(acc, 0, ax, sW0, t16, q);
  write_pre(pre, sW1, tid); pre = load_pre(pW + PW_IH + 2 * PW_CHUNK, tid);
  __syncthreads();
  mfma6(acc, 6, ax, sW1, t16, q);
  write_pre(pre, sW0, tid); pre = load_pre(pW + PW_IH + 3 * PW_CHUNK, tid);
  __syncthreads();
  mfma6(acc, 12, ax, sW0, t16, q);
  write_pre(pre, sW1, tid); pre = load_pre(pW + PW_HH, tid);
  __syncthreads();
  mfma6(acc, 18, ax, sW1, t16, q);
  write_pre(pre, sW0, tid); pre = load_pre(pW + PW_HH + PW_CHUNK, tid);
  __syncthreads();
  mfma6(acc, 0, ah, sW0, t16, q);
  write_pre(pre, sW1, tid); pre = load_pre(pW + PW_HH + 2 * PW_CHUNK, tid);
  __syncthreads();
  mfma6(acc, 6, ah, sW1, t16, q);
  write_pre(pre, sW0, tid); pre = load_pre(pW + PW_HH + 3 * PW_CHUNK, tid);
  __syncthreads();
  mfma6(acc, 12, ah, sW0, t16, q);
  write_pre(pre, sW1, tid); pre = load_pre(pW + 10 * PW_CHUNK, tid);
  __syncthreads();
  mfma6(acc, 18, ah, sW1, t16, q);
  write_pre(pre, sW0, tid); pre = load_pre(pW + 11 * PW_CHUNK, tid);
  __syncthreads();

  // P11: LSTM epilogue + readout L1 (rW12_0 in sW0)
  #pragma unroll
  for (int jt = 0; jt < 6; jt++)
    #pragma unroll
    for (int j = 0; j < 4; j++){
      size_t m = rbase + wrow + q * 4 + j;
      int col = jt * 16 + t16;
      float iv = acc[0 * 6 + jt][j];
      float fv = acc[1 * 6 + jt][j];
      float gv = acc[2 * 6 + jt][j];
      float ov = acc[3 * 6 + jt][j];
      float cold = cin[m * 96 + col];
      float cn = sigf(fv) * cold + sigf(iv) * tanhf_(gv);
      float hn = sigf(ov) * tanhf_(cn);
      cout[m * 96 + col] = cn;
      u16 hb = f2bf(hn);
      h[m * 96 + col] = hb;
      sA[(wrow + q * 4 + j) * LDP + col] = hb;
    }
  { Frags f = load_afrags_s(sA, wrow, lane);
    waves_layer(f, sW0, rb12, sA, LDP, wrow, true, lane); }
  write_pre(pre, sW1, tid);
  __syncthreads();

  // P12: readout L2
  { Frags f = load_afrags_s(sA, wrow, lane);
    waves_layer(f, sW1, rb12 + 96, sA, LDP, wrow, true, lane); }
  __syncthreads();

  // Final dot
  int row = tid >> 2, part = tid & 3;
  float s = 0.f;
  const u16* rp = sA + row * LDP + part * 24;
  #pragma unroll
  for (int k = 0; k < 24; k++) s += bf2f(rp[k]) * sw3[part * 24 + k];
  s += __shfl_xor(s, 1);
  s += __shfl_xor(s, 2);
  if (part == 0) out[rbase + row] = s + rb3[0];
}

// ============================================================================
extern "C" void kernel_launch(void* const* d_in, const int* in_sizes, int n_in,
                              void* d_out, int out_size, void* d_ws, size_t ws_size,
                              hipStream_t stream)
{
  (void)in_sizes; (void)n_in; (void)out_size; (void)ws_size;
  const int*   inputs = (const int*)d_in[0];
  const float* c0     = (const float*)d_in[1];
  const float* eW1  = (const float*)d_in[4];
  const float* eb1  = (const float*)d_in[5];
  const float* eW2  = (const float*)d_in[6];
  const float* eb2  = (const float*)d_in[7];
  const float* crW  = (const float*)d_in[8];
  const float* crB  = (const float*)d_in[9];
  const float* drW  = (const float*)d_in[10];
  const float* drB  = (const float*)d_in[11];
  const float* gmW1 = (const float*)d_in[12];
  const float* gmb1 = (const float*)d_in[13];
  const float* gmW2 = (const float*)d_in[14];
  const float* gmb2 = (const float*)d_in[15];
  const float* Wih  = (const float*)d_in[16];
  const float* Whh  = (const float*)d_in[17];
  const float* bih  = (const float*)d_in[18];
  const float* bhh  = (const float*)d_in[19];
  const float* rW12 = (const float*)d_in[20];
  const float* rb12 = (const float*)d_in[21];
  const float* rW3  = (const float*)d_in[22];
  const float* rb3  = (const float*)d_in[23];

  char* ws = (char*)d_ws;
  float* XgTab = (float*)(ws);
  float* XTab  = (float*)(ws + 4096);
  float* zb    = (float*)(ws + 6144);
  u16*   pW    = (u16*)(ws + 8192);
  u16* h  = (u16*)(ws + 8192 + 401408);
  u16* B1 = h  + (size_t)MROWS * 96;               // Y
  u16* B2 = B1 + (size_t)MROWS * 96;               // Z / Zd
  float* c = (float*)(B2 + (size_t)MROWS * 96);
  u16* Ssum = (u16*)(c + (size_t)MROWS * 96);      // BN*96 bf16 (~2 MB)
  float* out = (float*)d_out;

  k_prep<<<16, 256, 0, stream>>>(crW, drW, gmW1, gmW2, rW12, Wih, Whh, pW);
  k_tables<<<1, 128, 0, stream>>>(eW1, eb1, eW2, eb2, gmW1, gmb1, XTab, XgTab, zb);
  k_init<<<(MROWS * 12) / 256, 256, 0, stream>>>(inputs, XTab, h);

  for (int it = 0; it < 4; ++it){
    const float* cin = (it == 0) ? c0 : c;
    k_ab2<<<GRID_TILE, 256, 0, stream>>>(h, B1, B2, pW, crB, drB, zb);
    k_scell<<<(BN * 12) / 256, 256, 0, stream>>>(B1, Ssum);
    k_msgdigit<<<128 * 9, 256, 0, stream>>>(B2);
    k_glr2<<<GRID_TILE, 256, 0, stream>>>(B1, B2, Ssum, inputs, XgTab, pW, gmb2,
                                          h, cin, c, bih, bhh, rb12, rW3, rb3,
                                          out + (size_t)it * MROWS);
  }
}